// Round 1
// baseline (1764.476 us; speedup 1.0000x reference)
//
#include <hip/hip_runtime.h>

// GRU last-hidden: B=1024, C=64, T=1024, H=32, G=3H=96, all fp32.
// x: (B, C, T); W_ih: (96,64); W_hh: (96,32); b_ih,b_hh: (96,)
// out: (B, 32) = h after T steps.
//
// One block per batch. 192 threads (3 waves).
// Per 32-step time tile:
//   stage1: all 192 threads compute gx[t][g] = b_ih[g] + sum_c W_ih[g][c]*x[b][c][t]
//           (4t x 4g register tile per thread; W_ih^T staged in LDS once)
//   stage2: lanes 0..31 of wave0 run the recurrence; W_hh rows in registers,
//           h broadcast via __shfl within the 32-lane group (no LDS, no barriers).

#define Ck 64
#define Tk 1024
#define Hk 32
#define Gk 96
#define TT 32
#define XS_PAD 36    // xs row stride (pad to break bank conflicts)
#define GX_PAD 100   // gxs row stride

__global__ __launch_bounds__(192) void gru_fused(
    const float* __restrict__ x,
    const float* __restrict__ W_ih,
    const float* __restrict__ W_hh,
    const float* __restrict__ b_ih,
    const float* __restrict__ b_hh,
    float* __restrict__ out)
{
    __shared__ float wt[Ck * Gk];        // wt[c*96+g] = W_ih[g][c]   (24 KB)
    __shared__ float xs[Ck * XS_PAD];    // xs[c*36+t]                ( 9 KB)
    __shared__ float gxs[TT * GX_PAD];   // gxs[t*100+g]              (12.5 KB)

    const int tid = threadIdx.x;
    const int b   = blockIdx.x;
    const float* xb = x + (size_t)b * Ck * Tk;

    // ---- one-time: W_ih^T into LDS (coalesced global read) ----
    for (int i = tid; i < Gk * Ck; i += 192) {
        int g = i >> 6;      // row of W_ih
        int c = i & 63;
        wt[c * Gk + g] = W_ih[i];
    }

    // ---- stage-1 per-thread tile coords ----
    const int g4 = tid % 24;
    const int t4 = tid / 24;          // 0..7
    const int g0 = g4 * 4;
    const int t0 = t4 * 4;
    const float4 bi4 = *(const float4*)(b_ih + g0);   // g0 % 4 == 0 -> aligned

    // ---- stage-2 per-thread state (lanes 0..31 of wave0) ----
    float whr[Hk], whz[Hk], whn[Hk];
    float bhr = 0.f, bhz = 0.f, bhn = 0.f;
    float h = 0.f;
    if (tid < Hk) {
        #pragma unroll
        for (int k = 0; k < Hk; ++k) {
            whr[k] = W_hh[(0 * Hk + tid) * Hk + k];
            whz[k] = W_hh[(1 * Hk + tid) * Hk + k];
            whn[k] = W_hh[(2 * Hk + tid) * Hk + k];
        }
        bhr = b_hh[tid];
        bhz = b_hh[Hk + tid];
        bhn = b_hh[2 * Hk + tid];
    }

    for (int tile = 0; tile < Tk / TT; ++tile) {
        const int tbase = tile * TT;

        __syncthreads();   // previous stage2 done reading gxs / xs free; wt ready on iter 0

        // ---- load x tile: 64 rows x 32 t, coalesced along t ----
        {
            const float* src = xb + tbase;
            for (int i = tid; i < (Ck * TT / 4); i += 192) {   // 512 float4s
                int c  = i >> 3;
                int tq = i & 7;
                float4 v = *(const float4*)(src + c * Tk + tq * 4);
                *(float4*)(&xs[c * XS_PAD + tq * 4]) = v;
            }
        }
        __syncthreads();

        // ---- stage 1: gx tile (4t x 4g per thread) ----
        {
            float acc0x = bi4.x, acc0y = bi4.y, acc0z = bi4.z, acc0w = bi4.w;
            float acc1x = bi4.x, acc1y = bi4.y, acc1z = bi4.z, acc1w = bi4.w;
            float acc2x = bi4.x, acc2y = bi4.y, acc2z = bi4.z, acc2w = bi4.w;
            float acc3x = bi4.x, acc3y = bi4.y, acc3z = bi4.z, acc3w = bi4.w;
            #pragma unroll 4
            for (int c = 0; c < Ck; ++c) {
                float4 xv = *(const float4*)(&xs[c * XS_PAD + t0]);
                float4 wv = *(const float4*)(&wt[c * Gk + g0]);
                acc0x += xv.x * wv.x; acc0y += xv.x * wv.y; acc0z += xv.x * wv.z; acc0w += xv.x * wv.w;
                acc1x += xv.y * wv.x; acc1y += xv.y * wv.y; acc1z += xv.y * wv.z; acc1w += xv.y * wv.w;
                acc2x += xv.z * wv.x; acc2y += xv.z * wv.y; acc2z += xv.z * wv.z; acc2w += xv.z * wv.w;
                acc3x += xv.w * wv.x; acc3y += xv.w * wv.y; acc3z += xv.w * wv.z; acc3w += xv.w * wv.w;
            }
            float4 r0 = {acc0x, acc0y, acc0z, acc0w};
            float4 r1 = {acc1x, acc1y, acc1z, acc1w};
            float4 r2 = {acc2x, acc2y, acc2z, acc2w};
            float4 r3 = {acc3x, acc3y, acc3z, acc3w};
            *(float4*)(&gxs[(t0 + 0) * GX_PAD + g0]) = r0;
            *(float4*)(&gxs[(t0 + 1) * GX_PAD + g0]) = r1;
            *(float4*)(&gxs[(t0 + 2) * GX_PAD + g0]) = r2;
            *(float4*)(&gxs[(t0 + 3) * GX_PAD + g0]) = r3;
        }
        __syncthreads();

        // ---- stage 2: recurrence, lanes 0..31 of wave0 only ----
        if (tid < Hk) {
            for (int s = 0; s < TT; ++s) {
                float xr = gxs[s * GX_PAD + tid];
                float xz = gxs[s * GX_PAD + Hk + tid];
                float xn = gxs[s * GX_PAD + 2 * Hk + tid];
                float ar = bhr, az = bhz, an = bhn;
                #pragma unroll
                for (int k = 0; k < Hk; ++k) {
                    float hk = __shfl(h, k, 32);
                    ar += whr[k] * hk;
                    az += whz[k] * hk;
                    an += whn[k] * hk;
                }
                float r = 1.f / (1.f + __expf(-(xr + ar)));
                float z = 1.f / (1.f + __expf(-(xz + az)));
                float nx = xn + r * an;
                float n = 1.f - 2.f / (__expf(2.f * nx) + 1.f);   // tanh(nx)
                h = (1.f - z) * n + z * h;
            }
        }
    }

    if (tid < Hk) out[b * Hk + tid] = h;
}

extern "C" void kernel_launch(void* const* d_in, const int* in_sizes, int n_in,
                              void* d_out, int out_size, void* d_ws, size_t ws_size,
                              hipStream_t stream) {
    const float* x    = (const float*)d_in[0];
    const float* W_ih = (const float*)d_in[1];
    const float* W_hh = (const float*)d_in[2];
    const float* b_ih = (const float*)d_in[3];
    const float* b_hh = (const float*)d_in[4];
    float* out = (float*)d_out;

    gru_fused<<<1024, 192, 0, stream>>>(x, W_ih, W_hh, b_ih, b_hh, out);
}

// Round 2
// 649.323 us; speedup vs baseline: 2.7174x; 2.7174x over previous
//
#include <hip/hip_runtime.h>

// GRU last-hidden: B=1024, C=64, T=1024, H=32, G=96, fp32.
// x:(B,64,1024) W_ih:(96,64) W_hh:(96,32) b_ih,b_hh:(96) out:(B,32)
//
// 256 blocks x 512 threads; block = 4 batches (NB=4), 8 waves:
//   waves 0-3 = producers: gx tile GEMM for tile k+1 (batch = wid)
//   waves 4-7 = consumers: recurrence for tile k (batch = wid-4),
//               k-split-2 across the 64 lanes (lane = kh*32 + h)
// x staged async via global_load_lds one tile ahead; gxs double-buffered.
//
// Dynamic LDS (159744 B):
//   wt  [64][96]          = 24576 B  (W_ih^T)
//   xs  [4][64][32]       = 32768 B  (unpadded: global_load_lds dest is linear)
//   gxs [2][4][32][100]   = 102400 B (pad 96->100 keeps float4 align, spreads banks)

#define TT 32
#define GXS 100
#define LDS_BYTES 159744

#define GLL16(gp, lp)                                                        \
  __builtin_amdgcn_global_load_lds(                                          \
      (const __attribute__((address_space(1))) void*)(gp),                   \
      (__attribute__((address_space(3))) void*)(lp), 16, 0, 0)

__global__ __launch_bounds__(512) void gru_fused2(
    const float* __restrict__ x,
    const float* __restrict__ W_ih,
    const float* __restrict__ W_hh,
    const float* __restrict__ b_ih,
    const float* __restrict__ b_hh,
    float* __restrict__ out)
{
    extern __shared__ float smem[];
    float* wt  = smem;                 // 6144 floats
    float* xs  = smem + 6144;          // 8192 floats
    float* gxs = smem + 6144 + 8192;   // 25600 floats

    const int tid  = threadIdx.x;
    const int wid  = tid >> 6;
    const int lane = tid & 63;
    const int bid  = blockIdx.x;

    // ---- one-time: W_ih^T -> LDS (all threads) ----
    for (int i = tid; i < 96 * 64; i += 512) {
        int g = i >> 6, c = i & 63;
        wt[c * 96 + g] = W_ih[i];
    }

    // ================= producer state =================
    const int tg = lane >> 3, gg = lane & 7;
    const int t0 = tg * 4,  g0 = gg * 12;
    float bi[12];
    const float* xb = nullptr;
    if (wid < 4) {
        const int batch = bid * 4 + wid;
        xb = x + (size_t)batch * 64 * 1024;
        #pragma unroll
        for (int j = 0; j < 12; ++j) bi[j] = b_ih[g0 + j];
    }

    // ================= consumer state =================
    float whr[16], whz[16], whn[16];
    float bhr = 0.f, bhz = 0.f, bhn = 0.f, hcur = 0.f;
    const int kh = lane >> 5, h = lane & 31;
    if (wid >= 4) {
        const int k0 = kh * 16;
        #pragma unroll
        for (int j = 0; j < 16; ++j) {
            whr[j] = W_hh[(h)      * 32 + k0 + j];
            whz[j] = W_hh[(32 + h) * 32 + k0 + j];
            whn[j] = W_hh[(64 + h) * 32 + k0 + j];
        }
        bhr = b_hh[h]; bhz = b_hh[32 + h]; bhn = b_hh[64 + h];
    }

    // async x-tile load: wave wid loads its own batch's 8KB (8 x 1KB gll)
    auto load_xtile = [&](int tile) {
        const int tbase = tile * TT;
        const int c_lo = lane >> 3, toff = (lane & 7) * 4;
        #pragma unroll
        for (int i = 0; i < 8; ++i) {
            const float* gp = xb + (i * 8 + c_lo) * 1024 + tbase + toff;
            float* lp = xs + wid * 2048 + i * 256;   // wave-uniform base
            GLL16(gp, lp);
        }
    };

    // producer: gx tile GEMM from xs -> gxs[buf]
    auto stage1 = [&](int buf) {
        float acc[4][12];
        #pragma unroll
        for (int i = 0; i < 4; ++i)
            #pragma unroll
            for (int j = 0; j < 12; ++j) acc[i][j] = bi[j];
        const float* xrow = xs + wid * 2048;
        #pragma unroll 4
        for (int c = 0; c < 64; ++c) {
            float4 xv = *(const float4*)(xrow + c * 32 + t0);
            const float* wrow = wt + c * 96 + g0;
            float4 w0 = *(const float4*)(wrow);
            float4 w1 = *(const float4*)(wrow + 4);
            float4 w2 = *(const float4*)(wrow + 8);
            const float xc[4] = {xv.x, xv.y, xv.z, xv.w};
            #pragma unroll
            for (int i = 0; i < 4; ++i) {
                acc[i][0] += xc[i]*w0.x;  acc[i][1] += xc[i]*w0.y;
                acc[i][2] += xc[i]*w0.z;  acc[i][3] += xc[i]*w0.w;
                acc[i][4] += xc[i]*w1.x;  acc[i][5] += xc[i]*w1.y;
                acc[i][6] += xc[i]*w1.z;  acc[i][7] += xc[i]*w1.w;
                acc[i][8] += xc[i]*w2.x;  acc[i][9] += xc[i]*w2.y;
                acc[i][10] += xc[i]*w2.z; acc[i][11] += xc[i]*w2.w;
            }
        }
        float* gb = gxs + buf * 12800 + wid * 3200;
        #pragma unroll
        for (int i = 0; i < 4; ++i) {
            float* row = gb + (t0 + i) * GXS + g0;
            *(float4*)(row)     = make_float4(acc[i][0], acc[i][1], acc[i][2],  acc[i][3]);
            *(float4*)(row + 4) = make_float4(acc[i][4], acc[i][5], acc[i][6],  acc[i][7]);
            *(float4*)(row + 8) = make_float4(acc[i][8], acc[i][9], acc[i][10], acc[i][11]);
        }
    };

    // consumer: 32 recurrence steps on gxs[buf]
    auto stage2 = [&](int buf) {
        const float* gb = gxs + buf * 12800 + (wid - 4) * 3200;
        for (int s = 0; s < TT; ++s) {
            const float* row = gb + s * GXS;
            float xr = row[h], xz = row[32 + h], xn = row[64 + h];
            float ar = 0.f, az = 0.f, an = 0.f;
            #pragma unroll
            for (int j = 0; j < 16; ++j) {
                float hk = __shfl(hcur, kh * 16 + j, 64);  // lanes 0-31 hold h[0..31]
                ar += whr[j] * hk;
                az += whz[j] * hk;
                an += whn[j] * hk;
            }
            ar += __shfl_xor(ar, 32, 64);
            az += __shfl_xor(az, 32, 64);
            an += __shfl_xor(an, 32, 64);
            float r = 1.f / (1.f + __expf(-(xr + ar + bhr)));
            float z = 1.f / (1.f + __expf(-(xz + az + bhz)));
            float nx = xn + r * (an + bhn);
            float n  = 1.f - 2.f / (__expf(2.f * nx) + 1.f);   // tanh
            hcur = n + z * (hcur - n);
        }
    };

    // ================= pipeline =================
    if (wid < 4) load_xtile(0);
    __syncthreads();                       // wt ready; xs = tile 0

    if (wid < 4) {
        stage1(0);                         // gxs[0] = tile 0
        asm volatile("s_waitcnt lgkmcnt(0)" ::: "memory");  // xs reads done
        load_xtile(1);                     // overwrite own xs region
    }
    __syncthreads();                       // gxs[0] ready; xs = tile 1 (vmcnt drained)

    for (int k = 0; k < 32; ++k) {
        if (wid >= 4) {
            stage2(k & 1);
        } else if (k < 31) {
            stage1((k + 1) & 1);           // reads xs = tile k+1
            asm volatile("s_waitcnt lgkmcnt(0)" ::: "memory");
            if (k < 30) load_xtile(k + 2);
        }
        __syncthreads();
    }

    if (wid >= 4 && lane < 32) {
        const int batch = bid * 4 + (wid - 4);
        out[batch * 32 + lane] = hcur;
    }
}

extern "C" void kernel_launch(void* const* d_in, const int* in_sizes, int n_in,
                              void* d_out, int out_size, void* d_ws, size_t ws_size,
                              hipStream_t stream) {
    const float* x    = (const float*)d_in[0];
    const float* W_ih = (const float*)d_in[1];
    const float* W_hh = (const float*)d_in[2];
    const float* b_ih = (const float*)d_in[3];
    const float* b_hh = (const float*)d_in[4];
    float* out = (float*)d_out;

    hipFuncSetAttribute((const void*)gru_fused2,
                        hipFuncAttributeMaxDynamicSharedMemorySize, LDS_BYTES);
    gru_fused2<<<256, 512, LDS_BYTES, stream>>>(x, W_ih, W_hh, b_ih, b_hh, out);
}

// Round 3
// 536.722 us; speedup vs baseline: 3.2875x; 1.2098x over previous
//
#include <hip/hip_runtime.h>

// GRU last-hidden: B=1024, C=64, T=1024, H=32, G=96, fp32.
// x:(B,64,1024) W_ih:(96,64) W_hh:(96,32) b_ih,b_hh:(96) out:(B,32)
//
// 256 blocks x 512 threads; block = 4 batches, 8 waves:
//   waves 0-3 = producers: gx tile (32t x 96g) via MFMA bf16 hi/lo 3-product
//               split (error ~2^-16, fp32-grade), batch = wid
//   waves 4-7 = consumers: recurrence for tile k, batch = wid-4. No k-split:
//               h broadcast via v_readlane -> SGPR -> v_fmac (ZERO ds ops in
//               the matvec; R2's 16 ds_bpermute/step saturated the LDS pipe).
//
// LDS (159744 B):
//   wfH/wfL: W_ih in MFMA B-frag layout bf16 hi/lo  [2kt][6nt][64lane][8]  24576 B
//   xs:      x tiles, [4 wave][64 c][32 t], t XOR-swizzled by (c>>3)&3      32768 B
//   gxs:     [2 buf][4 batch][32 t][100 g] fp32                            102400 B

typedef short bf16x8 __attribute__((ext_vector_type(8)));
typedef float f32x4  __attribute__((ext_vector_type(4)));

#define TT 32
#define GXS 100
#define LDS_BYTES 159744

#define GLL16(gp, lp)                                                        \
  __builtin_amdgcn_global_load_lds(                                          \
      (const __attribute__((address_space(1))) void*)(gp),                   \
      (__attribute__((address_space(3))) void*)(lp), 16, 0, 0)

static __device__ __forceinline__ short f2bf(float f) {   // RNE float->bf16
    unsigned u = __float_as_uint(f);
    u += 0x7fffu + ((u >> 16) & 1u);
    return (short)(u >> 16);
}
static __device__ __forceinline__ float bf2f(short s) {
    return __uint_as_float(((unsigned)(unsigned short)s) << 16);
}

__global__ __launch_bounds__(512) void gru_fused3(
    const float* __restrict__ x,
    const float* __restrict__ W_ih,
    const float* __restrict__ W_hh,
    const float* __restrict__ b_ih,
    const float* __restrict__ b_hh,
    float* __restrict__ out)
{
    extern __shared__ char smem[];
    short* wfH = (short*)smem;                    // 768 frags * 8 shorts
    short* wfL = (short*)(smem + 12288);
    float* xs  = (float*)(smem + 24576);          // 4 * 2048 floats
    float* gxs = (float*)(smem + 57344);          // 2*4*32*100 floats

    const int tid  = threadIdx.x;
    const int wid  = tid >> 6;
    const int lane = tid & 63;
    const int bid  = blockIdx.x;

    // ---- one-time: W_ih -> bf16 hi/lo MFMA B-fragments in LDS ----
    // frag (kt,nt): lane slot holds W[g = nt*16+(slot&15)][c = kt*32+(slot>>4)*8 + j]
    for (int f = tid; f < 768; f += 512) {
        int slot = f & 63, ktnt = f >> 6;
        int kt = ktnt / 6, nt = ktnt - kt * 6;
        int g  = nt * 16 + (slot & 15);
        int c0 = kt * 32 + (slot >> 4) * 8;
        const float* wr = W_ih + g * 64 + c0;
        bf16x8 hi, lo;
        #pragma unroll
        for (int j = 0; j < 8; ++j) {
            float v  = wr[j];
            short hb = f2bf(v);
            hi[j] = hb;
            lo[j] = f2bf(v - bf2f(hb));
        }
        *(bf16x8*)(wfH + f * 8) = hi;
        *(bf16x8*)(wfL + f * 8) = lo;
    }

    // ================= producer state =================
    const float* xb = nullptr;
    float bias6[6];
    if (wid < 4) {
        xb = x + (size_t)(bid * 4 + wid) * 64 * 1024;
        #pragma unroll
        for (int nt = 0; nt < 6; ++nt) bias6[nt] = b_ih[nt * 16 + (lane & 15)];
    }

    // ================= consumer state =================
    float whr[32], whz[32], whn[32];
    float bhr = 0.f, bhz = 0.f, bhn = 0.f, hcur = 0.f;
    const int h = lane & 31;
    if (wid >= 4) {
        #pragma unroll
        for (int k = 0; k < 32; ++k) {
            whr[k] = W_hh[(h)      * 32 + k];
            whz[k] = W_hh[(32 + h) * 32 + k];
            whn[k] = W_hh[(64 + h) * 32 + k];
        }
        bhr = b_hh[h]; bhz = b_hh[32 + h]; bhn = b_hh[64 + h];
    }

    // async x-tile: lands as xs[c][t ^ (((c>>3)&3)<<2)] (XOR applied to the
    // GLOBAL source t-offset; LDS dest stays linear) -> conflict-free A-reads
    auto load_xtile = [&](int tile) {
        const int tbase = tile * TT;
        const int c_lo  = lane >> 3;
        #pragma unroll
        for (int i = 0; i < 8; ++i) {
            const int toff = ((lane & 7) ^ (i & 3)) << 2;
            const float* gp = xb + (i * 8 + c_lo) * 1024 + tbase + toff;
            float* lp = xs + wid * 2048 + i * 256;   // wave-uniform base
            GLL16(gp, lp);
        }
    };

    // producer: gx tile via MFMA; optionally prefetch next x tile mid-stage
    auto stage1 = [&](int buf, int prefetch_tile) {
        // A-frags: x^T (m=t, k=c), lane holds m=lane&15, k=(lane>>4)*8+j
        bf16x8 ah[2][2], al[2][2];
        #pragma unroll
        for (int mt = 0; mt < 2; ++mt) {
            const int tS = (mt * 16 + (lane & 15)) ^ ((lane >> 4) << 2);
            #pragma unroll
            for (int kt = 0; kt < 2; ++kt) {
                const int cb = kt * 32 + (lane >> 4) * 8;
                float xf[8];
                #pragma unroll
                for (int j = 0; j < 8; ++j)
                    xf[j] = xs[wid * 2048 + (cb + j) * 32 + tS];
                #pragma unroll
                for (int j = 0; j < 8; ++j) {
                    short hb = f2bf(xf[j]);
                    ah[mt][kt][j] = hb;
                    al[mt][kt][j] = f2bf(xf[j] - bf2f(hb));
                }
            }
        }
        // xs reads drained -> safe to overwrite own xs region
        asm volatile("s_waitcnt lgkmcnt(0)" ::: "memory");
        if (prefetch_tile >= 0) load_xtile(prefetch_tile);

        float* gb = gxs + buf * 12800 + wid * 3200;
        #pragma unroll
        for (int nt = 0; nt < 6; ++nt) {
            bf16x8 bh0 = *(const bf16x8*)(wfH + ((nt)     * 64 + lane) * 8);
            bf16x8 bh1 = *(const bf16x8*)(wfH + ((6 + nt) * 64 + lane) * 8);
            bf16x8 bl0 = *(const bf16x8*)(wfL + ((nt)     * 64 + lane) * 8);
            bf16x8 bl1 = *(const bf16x8*)(wfL + ((6 + nt) * 64 + lane) * 8);
            const float bias = bias6[nt];
            #pragma unroll
            for (int mt = 0; mt < 2; ++mt) {
                f32x4 acc = {bias, bias, bias, bias};
                acc = __builtin_amdgcn_mfma_f32_16x16x32_bf16(ah[mt][0], bh0, acc, 0, 0, 0);
                acc = __builtin_amdgcn_mfma_f32_16x16x32_bf16(ah[mt][1], bh1, acc, 0, 0, 0);
                acc = __builtin_amdgcn_mfma_f32_16x16x32_bf16(ah[mt][0], bl0, acc, 0, 0, 0);
                acc = __builtin_amdgcn_mfma_f32_16x16x32_bf16(ah[mt][1], bl1, acc, 0, 0, 0);
                acc = __builtin_amdgcn_mfma_f32_16x16x32_bf16(al[mt][0], bh0, acc, 0, 0, 0);
                acc = __builtin_amdgcn_mfma_f32_16x16x32_bf16(al[mt][1], bh1, acc, 0, 0, 0);
                // C layout: col = lane&15 (g), row = (lane>>4)*4 + reg (t)
                const int row0 = mt * 16 + ((lane >> 4) << 2);
                const int col  = nt * 16 + (lane & 15);
                #pragma unroll
                for (int j = 0; j < 4; ++j)
                    gb[(row0 + j) * GXS + col] = acc[j];
            }
        }
    };

    // consumer: 32 steps; matvec via readlane(SGPR) broadcast, zero DS ops
    auto stage2 = [&](int buf) {
        const float* gb = gxs + buf * 12800 + (wid - 4) * 3200;
        #pragma unroll 2
        for (int s = 0; s < TT; ++s) {
            const float* row = gb + s * GXS;
            float xr = row[h], xz = row[32 + h], xn = row[64 + h];
            float ar0 = 0.f, ar1 = 0.f, az0 = 0.f, az1 = 0.f, an0 = 0.f, an1 = 0.f;
            const int hb = __float_as_int(hcur);
            #pragma unroll
            for (int j = 0; j < 32; j += 2) {
                float h0 = __int_as_float(__builtin_amdgcn_readlane(hb, j));
                float h1 = __int_as_float(__builtin_amdgcn_readlane(hb, j + 1));
                ar0 = fmaf(whr[j], h0, ar0);  ar1 = fmaf(whr[j + 1], h1, ar1);
                az0 = fmaf(whz[j], h0, az0);  az1 = fmaf(whz[j + 1], h1, az1);
                an0 = fmaf(whn[j], h0, an0);  an1 = fmaf(whn[j + 1], h1, an1);
            }
            float r  = 1.f / (1.f + __expf(-(xr + ar0 + ar1 + bhr)));
            float z  = 1.f / (1.f + __expf(-(xz + az0 + az1 + bhz)));
            float nx = xn + r * (an0 + an1 + bhn);
            float n  = 1.f - 2.f / (__expf(2.f * nx) + 1.f);   // tanh
            hcur = n + z * (hcur - n);
        }
    };

    // ================= pipeline =================
    if (wid < 4) load_xtile(0);
    __syncthreads();                    // wfrag ready; xs = tile 0 (vmcnt drained)

    if (wid < 4) stage1(0, 1);          // gxs[0] = tile 0; prefetch tile 1
    __syncthreads();                    // gxs[0] visible; xs = tile 1

    for (int k = 0; k < 32; ++k) {
        if (wid >= 4) {
            stage2(k & 1);
        } else if (k < 31) {
            stage1((k + 1) & 1, (k < 30) ? (k + 2) : -1);
        }
        __syncthreads();
    }

    if (wid >= 4 && lane < 32)
        out[(bid * 4 + (wid - 4)) * 32 + lane] = hcur;
}

extern "C" void kernel_launch(void* const* d_in, const int* in_sizes, int n_in,
                              void* d_out, int out_size, void* d_ws, size_t ws_size,
                              hipStream_t stream) {
    const float* x    = (const float*)d_in[0];
    const float* W_ih = (const float*)d_in[1];
    const float* W_hh = (const float*)d_in[2];
    const float* b_ih = (const float*)d_in[3];
    const float* b_hh = (const float*)d_in[4];
    float* out = (float*)d_out;

    hipFuncSetAttribute((const void*)gru_fused3,
                        hipFuncAttributeMaxDynamicSharedMemorySize, LDS_BYTES);
    gru_fused3<<<256, 512, LDS_BYTES, stream>>>(x, W_ih, W_hh, b_ih, b_hh, out);
}